// Round 6
// baseline (433.813 us; speedup 1.0000x reference)
//
#include <hip/hip_runtime.h>

namespace {

constexpr int kB = 4096;
constexpr int kT = 256;
constexpr int kLags = 32;
constexpr int kH = 128;
constexpr int kSteps = 255;   // 32 warmup + 223 AR steps
constexpr int kOut = 224;     // kT - kLags
constexpr int kMT = 16;       // batch rows in LDS/MFMA (rows 8-15 duplicate 0-7)
constexpr int kMTr = 8;       // REAL batches per block -> 512 blocks -> 2 blocks/CU
constexpr int kThreads = 256; // 4 waves; wave w owns outcols 32w..32w+31 (2 MFMA tiles)
constexpr int kHS = 136;      // bf16 row stride: 272 B (measured-benign banks)
constexpr int kOS = 225;      // obuf row stride
constexpr int kHLO = 2 * kMT * kHS;  // shorts: constant offset hhi[p][n] -> hlo[p][n]

// z-path pre-scale: 2 * log2(e). tanh(z) = 1 - 2/(exp2(2*log2e*z)+1),
// so v_exp_f32 (=exp2) needs no per-element 1/ln2 multiply.
constexpr float kZS = 2.8853900817779268f;

typedef __attribute__((ext_vector_type(8))) short short8;
typedef __attribute__((ext_vector_type(4))) float f32x4;

struct __align__(16) SMem {
    unsigned short hhi[2][kMT][kHS];  // h high bf16, [buf][batch][col]
    unsigned short hlo[2][kMT][kHS];  // h low  bf16 (MUST follow hhi: kHLO offset trick)
    float x0T[kT][kMT];               // feature 0, transposed [t][batch]
    float x1wT[kLags][kMT];           // feature 1 warmup, transposed
    float pbuf[2][4][kMT];            // per-wave Wd-partial staging (double-buffered)
    float obuf[kMT][kOS];             // ES output staging
};

__device__ __forceinline__ unsigned short bf16_rne(float f) {
    unsigned u = __builtin_bit_cast(unsigned, f);
    u += 0x7FFFu + ((u >> 16) & 1u);
    return (unsigned short)(u >> 16);
}
__device__ __forceinline__ float bf16_f32(unsigned short h) {
    unsigned u = ((unsigned)h) << 16;
    return __builtin_bit_cast(float, u);
}
// tanh(z) given zs = 2*log2(e)*z  (scale folded into weights, exact math)
__device__ __forceinline__ float tanh_from_zs(float zs) {
    float e = __builtin_amdgcn_exp2f(zs);
    return fmaf(-2.0f, __builtin_amdgcn_rcpf(e + 1.0f), 1.0f);
}
// RNE bf16 in TOP 16 bits (for v_perm byte [7,6]/[3,2] extraction)
__device__ __forceinline__ unsigned bf16_rne_hibits(float f) {
    unsigned u = __builtin_bit_cast(unsigned, f);
    return (u + (0x7FFFu + ((u >> 16) & 1u))) & 0xFFFF0000u;
}

__global__ __launch_bounds__(kThreads, 1)
void arx_rnn_es_kernel(const float* __restrict__ inputs,
                       const float* __restrict__ Wx,
                       const float* __restrict__ Wh,
                       const float* __restrict__ bias,
                       const float* __restrict__ Wd,
                       const float* __restrict__ bd,
                       const float* __restrict__ alpha,
                       float* __restrict__ out) {
    __shared__ SMem sm;
    const int tid  = threadIdx.x;
    const int b0   = blockIdx.x * kMTr;
    const int lane = tid & 63;
    const int w    = tid >> 6;        // wave 0..3, owns outcols 32w..32w+31
    const int n    = lane & 15;       // batch row (B-frag col & C col)
    const int q    = lane >> 4;       // quad: C rows 4q..4q+3 (= outcols in tile)

    // ---------------- one-time staging (rows 8-15 duplicate rows 0-7) ----------------
    for (int idx = tid; idx < kMT * kT; idx += kThreads) {
        const int mm = idx >> 8;
        const int t  = idx & 255;
        float2 v = ((const float2*)inputs)[(size_t)(b0 + (mm & 7)) * kT + t];
        sm.x0T[t][mm] = v.x;
        if (t < kLags) sm.x1wT[t][mm] = v.y;
    }
    for (int idx = tid; idx < kMT * kHS; idx += kThreads) {
        ((unsigned short*)sm.hhi[0])[idx] = 0;
        ((unsigned short*)sm.hlo[0])[idx] = 0;
    }

    const float av  = fminf(fmaxf(alpha[0], 0.0f), 1.0f);
    const float bdv = bd[0];

    // ---- epilogue constant vectors per tile (all z-path consts pre-scaled by kZS) ----
    f32x4 sb2v[2], swx0v[2], swx1ev[2], sbpv[2];
#pragma unroll
    for (int t = 0; t < 2; ++t) {
#pragma unroll
        for (int r = 0; r < 4; ++r) {
            const int colE = w * 32 + t * 16 + q * 4 + r;
            const float bc = bias[colE];
            const float w0 = Wx[colE];
            const float w1 = Wx[kH + colE];
            sb2v[t][r]   = kZS * bc;
            swx0v[t][r]  = kZS * w0;
            swx1ev[t][r] = kZS * w1;
            sbpv[t][r]   = kZS * (bc + bdv * w1);   // folded bias for AR steps
        }
    }
    __syncthreads();

    const f32x4 zero4 = {0.0f, 0.0f, 0.0f, 0.0f};
    int p = 0;

    // ================= warmup: st = 0..31 (unfolded kZS*Wh, real x1) ===============
    {
        short8 whh[2][4], whl[2][4];
#pragma unroll
        for (int t = 0; t < 2; ++t) {
            const int colw = w * 32 + t * 16 + n;
#pragma unroll
            for (int c = 0; c < 4; ++c) {
#pragma unroll
                for (int j = 0; j < 8; ++j) {
                    const int k = c * 32 + q * 8 + j;
                    float wv = kZS * Wh[(size_t)k * kH + colw];
                    unsigned short hi = bf16_rne(wv);
                    whh[t][c][j] = (short)hi;
                    whl[t][c][j] = (short)bf16_rne(wv - bf16_f32(hi));
                }
            }
        }

#pragma unroll 1
        for (int st = 0; st < kLags; ++st) {
            const float x0s = sm.x0T[st][n];
            const float x1s = sm.x1wT[st][n];

            const unsigned short* hb = (const unsigned short*)&sm.hhi[p][n][0];
            unsigned short* hw = (unsigned short*)&sm.hhi[p ^ 1][n][0];

            // hoist all 8 h-reads ahead of the MFMA sequence
            short8 bh[4], bl[4];
#pragma unroll
            for (int c = 0; c < 4; ++c) {
                bh[c] = *(const short8*)(hb + c * 32 + 8 * q);
                bl[c] = *(const short8*)(hb + kHLO + c * 32 + 8 * q);
            }

            // 3 accumulators x 2 tiles: six independent depth-4 MFMA chains.
            // Bias / x-terms seed the accumulators as MFMA C-inputs (no movs).
            f32x4 a1[2], a2[2], a3[2];
#pragma unroll
            for (int t = 0; t < 2; ++t) {
                f32x4 xi;
#pragma unroll
                for (int r = 0; r < 4; ++r)
                    xi[r] = fmaf(x0s, swx0v[t][r], x1s * swx1ev[t][r]);
                a1[t] = __builtin_amdgcn_mfma_f32_16x16x32_bf16(whh[t][0], bh[0], sb2v[t], 0, 0, 0);
                a2[t] = __builtin_amdgcn_mfma_f32_16x16x32_bf16(whl[t][0], bh[0], zero4,   0, 0, 0);
                a3[t] = __builtin_amdgcn_mfma_f32_16x16x32_bf16(whh[t][0], bl[0], xi,      0, 0, 0);
#pragma unroll
                for (int c = 1; c < 4; ++c) {
                    a1[t] = __builtin_amdgcn_mfma_f32_16x16x32_bf16(whh[t][c], bh[c], a1[t], 0, 0, 0);
                    a2[t] = __builtin_amdgcn_mfma_f32_16x16x32_bf16(whl[t][c], bh[c], a2[t], 0, 0, 0);
                    a3[t] = __builtin_amdgcn_mfma_f32_16x16x32_bf16(whh[t][c], bl[c], a3[t], 0, 0, 0);
                }
            }

#pragma unroll
            for (int t = 0; t < 2; ++t) {
                unsigned rb[4], db[4];
#pragma unroll
                for (int r = 0; r < 4; ++r) {
                    float zs = (a1[t][r] + a2[t][r]) + a3[t][r];
                    float hf = tanh_from_zs(zs);
                    rb[r] = bf16_rne_hibits(hf);
                    float d = hf - __builtin_bit_cast(float, rb[r]);
                    db[r] = __builtin_bit_cast(unsigned, d);   // trunc lo (top 16 bits)
                }
                uint2 uh, ul;
                uh.x = __builtin_amdgcn_perm(rb[1], rb[0], 0x07060302u);
                uh.y = __builtin_amdgcn_perm(rb[3], rb[2], 0x07060302u);
                ul.x = __builtin_amdgcn_perm(db[1], db[0], 0x07060302u);
                ul.y = __builtin_amdgcn_perm(db[3], db[2], 0x07060302u);
                *(uint2*)(hw + w * 32 + t * 16 + q * 4) = uh;
                *(uint2*)(hw + kHLO + w * 32 + t * 16 + q * 4) = ul;
            }

            __syncthreads();
            p ^= 1;
        }
    }

    // ---- folded AR weights kZS*(Wh + Wd*wx1^T) and per-wave Wd slice frag ----
    // dhw (pred path) is NOT kZS-scaled: pred = h.Wd + bd directly.
    short8 fhh[2][4], fhl[2][4], dhw;
    {
#pragma unroll
        for (int t = 0; t < 2; ++t) {
            const int colw = w * 32 + t * 16 + n;
            const float wx1w = Wx[kH + colw];
#pragma unroll
            for (int c = 0; c < 4; ++c) {
#pragma unroll
                for (int j = 0; j < 8; ++j) {
                    const int k = c * 32 + q * 8 + j;
                    float wv = kZS * fmaf(Wd[k], wx1w, Wh[(size_t)k * kH + colw]);
                    unsigned short hi = bf16_rne(wv);
                    fhh[t][c][j] = (short)hi;
                    fhl[t][c][j] = (short)bf16_rne(wv - bf16_f32(hi));
                }
            }
        }
#pragma unroll
        for (int j = 0; j < 8; ++j)
            dhw[j] = (short)bf16_rne(Wd[w * 32 + q * 8 + j]);  // k-slice w only
    }

    float es = 0.0f;   // wave 0, q==0 lanes: es for batch row n

    // ========= AR: st = 32..254. pred partials split across waves (1 MFMA each),
    // ========= ES recurrence finished one step deferred by wave 0 from pbuf.
#pragma unroll 1
    for (int st = kLags; st < kSteps; ++st) {
        const float x0s = sm.x0T[st][n];

        const unsigned short* hb = (const unsigned short*)&sm.hhi[p][n][0];
        unsigned short* hw = (unsigned short*)&sm.hhi[p ^ 1][n][0];

        short8 bh[4], bl[4];
#pragma unroll
        for (int c = 0; c < 4; ++c) {
            bh[c] = *(const short8*)(hb + c * 32 + 8 * q);
            bl[c] = *(const short8*)(hb + kHLO + c * 32 + 8 * q);
        }
        // wave's own k-slice, re-read to keep bh[] statically indexed (rule #20)
        short8 bhP = *(const short8*)(hb + w * 32 + 8 * q);

        f32x4 a1[2], a2[2], a3[2];
#pragma unroll
        for (int t = 0; t < 2; ++t) {
            f32x4 xi;
#pragma unroll
            for (int r = 0; r < 4; ++r) xi[r] = x0s * swx0v[t][r];
            a1[t] = __builtin_amdgcn_mfma_f32_16x16x32_bf16(fhh[t][0], bh[0], sbpv[t], 0, 0, 0);
            a2[t] = __builtin_amdgcn_mfma_f32_16x16x32_bf16(fhl[t][0], bh[0], zero4,   0, 0, 0);
            a3[t] = __builtin_amdgcn_mfma_f32_16x16x32_bf16(fhh[t][0], bl[0], xi,      0, 0, 0);
#pragma unroll
            for (int c = 1; c < 4; ++c) {
                a1[t] = __builtin_amdgcn_mfma_f32_16x16x32_bf16(fhh[t][c], bh[c], a1[t], 0, 0, 0);
                a2[t] = __builtin_amdgcn_mfma_f32_16x16x32_bf16(fhl[t][c], bh[c], a2[t], 0, 0, 0);
                a3[t] = __builtin_amdgcn_mfma_f32_16x16x32_bf16(fhh[t][c], bl[c], a3[t], 0, 0, 0);
            }
        }

        // pred partial for k-slice w: h_hi only (h_lo term ~3e-4, ES-smoothed)
        f32x4 P = __builtin_amdgcn_mfma_f32_16x16x32_bf16(dhw, bhP, zero4, 0, 0, 0);
        if (q == 0) sm.pbuf[p][w][n] = P[0];

        // deferred ES: finish pred of step st-1 from last step's partials
        if (w == 0 && q == 0 && st > kLags) {
            float pv = ((sm.pbuf[p ^ 1][0][n] + sm.pbuf[p ^ 1][1][n]) +
                        (sm.pbuf[p ^ 1][2][n] + sm.pbuf[p ^ 1][3][n])) + bdv;
            const int m = st - kLags - 1;
            es = (m == 0) ? pv : fmaf(av, pv - es, es);
            sm.obuf[n][m] = es;
        }

#pragma unroll
        for (int t = 0; t < 2; ++t) {
            unsigned rb[4], db[4];
#pragma unroll
            for (int r = 0; r < 4; ++r) {
                float zs = (a1[t][r] + a2[t][r]) + a3[t][r];
                float hf = tanh_from_zs(zs);
                rb[r] = bf16_rne_hibits(hf);
                float d = hf - __builtin_bit_cast(float, rb[r]);
                db[r] = __builtin_bit_cast(unsigned, d);
            }
            uint2 uh, ul;
            uh.x = __builtin_amdgcn_perm(rb[1], rb[0], 0x07060302u);
            uh.y = __builtin_amdgcn_perm(rb[3], rb[2], 0x07060302u);
            ul.x = __builtin_amdgcn_perm(db[1], db[0], 0x07060302u);
            ul.y = __builtin_amdgcn_perm(db[3], db[2], 0x07060302u);
            *(uint2*)(hw + w * 32 + t * 16 + q * 4) = uh;
            *(uint2*)(hw + kHLO + w * 32 + t * 16 + q * 4) = ul;
        }

        __syncthreads();
        p ^= 1;
    }

    // ===== tail: finish pred_222 (pbuf[p^1]), then pred_223 from h_255 =====
    if (w == 0 && q == 0) {
        float pv = ((sm.pbuf[p ^ 1][0][n] + sm.pbuf[p ^ 1][1][n]) +
                    (sm.pbuf[p ^ 1][2][n] + sm.pbuf[p ^ 1][3][n])) + bdv;
        es = fmaf(av, pv - es, es);
        sm.obuf[n][kOut - 2] = es;
    }
    {
        const unsigned short* hb = (const unsigned short*)&sm.hhi[p][n][0];
        short8 bhP = *(const short8*)(hb + w * 32 + 8 * q);
        f32x4 P = __builtin_amdgcn_mfma_f32_16x16x32_bf16(dhw, bhP, zero4, 0, 0, 0);
        if (q == 0) sm.pbuf[p][w][n] = P[0];
    }
    __syncthreads();
    if (w == 0 && q == 0) {
        float pv = ((sm.pbuf[p][0][n] + sm.pbuf[p][1][n]) +
                    (sm.pbuf[p][2][n] + sm.pbuf[p][3][n])) + bdv;
        es = fmaf(av, pv - es, es);
        sm.obuf[n][kOut - 1] = es;
    }

    // ================= flush ES staging buffer to HBM (real rows 0-7 only) =========
    __syncthreads();
    for (int idx = tid; idx < kMTr * kOut; idx += kThreads) {
        const int mm = idx / kOut;
        const int t  = idx - mm * kOut;
        out[(size_t)(b0 + mm) * kOut + t] = sm.obuf[mm][t];
    }
}

}  // namespace

extern "C" void kernel_launch(void* const* d_in, const int* in_sizes, int n_in,
                              void* d_out, int out_size, void* d_ws, size_t ws_size,
                              hipStream_t stream) {
    const float* inputs = (const float*)d_in[0];
    const float* Wx     = (const float*)d_in[1];
    const float* Wh     = (const float*)d_in[2];
    const float* bias   = (const float*)d_in[3];
    const float* Wd     = (const float*)d_in[4];
    const float* bd     = (const float*)d_in[5];
    const float* alpha  = (const float*)d_in[6];
    // d_in[7] = lags (compile-time constant 32 here)

    arx_rnn_es_kernel<<<kB / kMTr, kThreads, 0, stream>>>(
        inputs, Wx, Wh, bias, Wd, bd, alpha, (float*)d_out);
}

// Round 7
// 211.735 us; speedup vs baseline: 2.0489x; 2.0489x over previous
//
#include <hip/hip_runtime.h>

namespace {

constexpr int kB = 4096;
constexpr int kT = 256;
constexpr int kLags = 32;
constexpr int kH = 128;
constexpr int kSteps = 255;   // 32 warmup + 223 AR steps
constexpr int kOut = 224;     // kT - kLags
constexpr int kMT = 16;       // batch rows per block
constexpr int kThreads = 512; // 8 waves; wave w owns outcols 16w..16w+15
constexpr int kHS = 136;      // bf16 row stride: 272 B (measured-benign banks)
constexpr int kOS = 225;      // obuf row stride
constexpr int kHLO = 2 * kMT * kHS;  // shorts: constant offset hhi[p][n] -> hlo[p][n]

// z-path pre-scale: 2 * log2(e). tanh(z) = 1 - 2/(exp2(2*log2e*z)+1),
// so v_exp_f32 (=exp2) needs no per-element 1/ln2 multiply.
constexpr float kZS = 2.8853900817779268f;

typedef __attribute__((ext_vector_type(8))) short short8;
typedef __attribute__((ext_vector_type(4))) float f32x4;

struct __align__(16) SMem {
    unsigned short hhi[2][kMT][kHS];  // h high bf16, [buf][batch][col]
    unsigned short hlo[2][kMT][kHS];  // h low  bf16 (MUST follow hhi: kHLO offset trick)
    float x0T[kT][kMT];               // feature 0, transposed [t][batch]
    float x1wT[kLags][kMT];           // feature 1 warmup, transposed
    float obuf[kMT][kOS];             // ES output staging
};

__device__ __forceinline__ unsigned short bf16_rne(float f) {
    unsigned u = __builtin_bit_cast(unsigned, f);
    u += 0x7FFFu + ((u >> 16) & 1u);
    return (unsigned short)(u >> 16);
}
__device__ __forceinline__ float bf16_f32(unsigned short h) {
    unsigned u = ((unsigned)h) << 16;
    return __builtin_bit_cast(float, u);
}
// tanh(z) given zs = 2*log2(e)*z  (scale folded into weights, exact math)
__device__ __forceinline__ float tanh_from_zs(float zs) {
    float e = __builtin_amdgcn_exp2f(zs);
    return fmaf(-2.0f, __builtin_amdgcn_rcpf(e + 1.0f), 1.0f);
}
// RNE bf16 in TOP 16 bits (for v_perm byte [7,6]/[3,2] extraction)
__device__ __forceinline__ unsigned bf16_rne_hibits(float f) {
    unsigned u = __builtin_bit_cast(unsigned, f);
    return (u + (0x7FFFu + ((u >> 16) & 1u))) & 0xFFFF0000u;
}

__global__ __launch_bounds__(kThreads, 2)
void arx_rnn_es_kernel(const float* __restrict__ inputs,
                       const float* __restrict__ Wx,
                       const float* __restrict__ Wh,
                       const float* __restrict__ bias,
                       const float* __restrict__ Wd,
                       const float* __restrict__ bd,
                       const float* __restrict__ alpha,
                       float* __restrict__ out) {
    __shared__ SMem sm;
    const int tid  = threadIdx.x;
    const int b0   = blockIdx.x * kMT;
    const int lane = tid & 63;
    const int w    = tid >> 6;        // wave 0..7, owns outcols 16w..16w+15
    const int n    = lane & 15;       // batch row (B-frag col & C col)
    const int q    = lane >> 4;       // quad: C rows 4q..4q+3 (= outcols in tile)

    // ---------------- one-time staging ----------------
    for (int idx = tid; idx < kMT * kT; idx += kThreads) {
        const int mm = idx >> 8;
        const int t  = idx & 255;
        float2 v = ((const float2*)inputs)[(size_t)(b0 + mm) * kT + t];
        sm.x0T[t][mm] = v.x;
        if (t < kLags) sm.x1wT[t][mm] = v.y;
    }
    for (int idx = tid; idx < kMT * kHS; idx += kThreads) {
        ((unsigned short*)sm.hhi[0])[idx] = 0;
        ((unsigned short*)sm.hlo[0])[idx] = 0;
    }

    const float av  = fminf(fmaxf(alpha[0], 0.0f), 1.0f);
    const float bdv = bd[0];

    // ---- epilogue constants (all z-path consts pre-scaled by kZS) ----
    f32x4 sb2v, swx0v, swx1ev, sbpv;
#pragma unroll
    for (int r = 0; r < 4; ++r) {
        const int colE = w * 16 + q * 4 + r;
        const float bc = bias[colE];
        const float w0 = Wx[colE];
        const float w1 = Wx[kH + colE];
        sb2v[r]   = kZS * bc;
        swx0v[r]  = kZS * w0;
        swx1ev[r] = kZS * w1;
        sbpv[r]   = kZS * (bc + bdv * w1);   // folded bias for AR steps
    }
    __syncthreads();

    const f32x4 zero4 = {0.0f, 0.0f, 0.0f, 0.0f};

    // loop-invariant LDS row pointers (unroll-2 makes buffer parity static)
    unsigned short* h0 = (unsigned short*)&sm.hhi[0][n][0];
    unsigned short* h1 = (unsigned short*)&sm.hhi[1][n][0];

    // ================= warmup: st = 0..31 (unfolded kZS*Wh, real x1) ===============
    {
        short8 whh[4], whl[4];
        {
            const int colw = w * 16 + n;
#pragma unroll
            for (int c = 0; c < 4; ++c) {
#pragma unroll
                for (int j = 0; j < 8; ++j) {
                    const int k = c * 32 + q * 8 + j;
                    float wv = kZS * Wh[(size_t)k * kH + colw];
                    unsigned short hi = bf16_rne(wv);
                    whh[c][j] = (short)hi;
                    whl[c][j] = (short)bf16_rne(wv - bf16_f32(hi));
                }
            }
        }

        // one warmup step: read hb, write hw. Reads interleaved with MFMA chains.
        auto warm_step = [&](const unsigned short* hb, unsigned short* hw, int st) {
            const float x0s = sm.x0T[st][n];
            const float x1s = sm.x1wT[st][n];
            f32x4 xi;
#pragma unroll
            for (int r = 0; r < 4; ++r)
                xi[r] = fmaf(x0s, swx0v[r], x1s * swx1ev[r]);

            f32x4 a1, a2, a3;
#pragma unroll
            for (int c = 0; c < 4; ++c) {
                short8 bh = *(const short8*)(hb + c * 32 + 8 * q);
                short8 bl = *(const short8*)(hb + kHLO + c * 32 + 8 * q);
                if (c == 0) {
                    a1 = __builtin_amdgcn_mfma_f32_16x16x32_bf16(whh[0], bh, sb2v, 0, 0, 0);
                    a2 = __builtin_amdgcn_mfma_f32_16x16x32_bf16(whl[0], bh, zero4, 0, 0, 0);
                    a3 = __builtin_amdgcn_mfma_f32_16x16x32_bf16(whh[0], bl, xi,   0, 0, 0);
                } else {
                    a1 = __builtin_amdgcn_mfma_f32_16x16x32_bf16(whh[c], bh, a1, 0, 0, 0);
                    a2 = __builtin_amdgcn_mfma_f32_16x16x32_bf16(whl[c], bh, a2, 0, 0, 0);
                    a3 = __builtin_amdgcn_mfma_f32_16x16x32_bf16(whh[c], bl, a3, 0, 0, 0);
                }
            }

            unsigned rb[4], db[4];
#pragma unroll
            for (int r = 0; r < 4; ++r) {
                float zs = (a1[r] + a2[r]) + a3[r];
                float hf = tanh_from_zs(zs);
                rb[r] = bf16_rne_hibits(hf);
                float d = hf - __builtin_bit_cast(float, rb[r]);
                db[r] = __builtin_bit_cast(unsigned, d);   // trunc lo (top 16 bits)
            }
            uint2 uh, ul;
            uh.x = __builtin_amdgcn_perm(rb[1], rb[0], 0x07060302u);
            uh.y = __builtin_amdgcn_perm(rb[3], rb[2], 0x07060302u);
            ul.x = __builtin_amdgcn_perm(db[1], db[0], 0x07060302u);
            ul.y = __builtin_amdgcn_perm(db[3], db[2], 0x07060302u);
            const int wcol = w * 16 + q * 4;
            *(uint2*)(hw + wcol) = uh;
            *(uint2*)(hw + kHLO + wcol) = ul;
        };

#pragma unroll 1
        for (int st = 0; st < kLags; st += 2) {
            warm_step(h0, h1, st);       // even step: buf0 -> buf1
            __syncthreads();
            warm_step(h1, h0, st + 1);   // odd step:  buf1 -> buf0
            __syncthreads();
        }
    }
    // h_32 now in buf0 (32 flips)

    // ---- folded AR weights kZS*(Wh + Wd*wx1^T) and Wd-replicated pred frag ----
    // dh (pred path) is NOT kZS-scaled: pred = h.Wd + bd directly.
    short8 fhh[4], fhl[4], dh[4];
    {
        const int colw = w * 16 + n;
        const float wx1w = Wx[kH + colw];
#pragma unroll
        for (int c = 0; c < 4; ++c) {
#pragma unroll
            for (int j = 0; j < 8; ++j) {
                const int k = c * 32 + q * 8 + j;
                float wv = kZS * fmaf(Wd[k], wx1w, Wh[(size_t)k * kH + colw]);
                unsigned short hi = bf16_rne(wv);
                fhh[c][j] = (short)hi;
                fhl[c][j] = (short)bf16_rne(wv - bf16_f32(hi));
                dh[c][j]  = (short)bf16_rne(Wd[k]);  // k-only: same for all rows
            }
        }
    }

    float es = 0.0f;   // wave 0, q==0 lanes: es for batch row n

    // one AR step: read hb, write hw. Reads interleaved with MFMA chains;
    // pred MFMA (w==0) rides the same bh fragments.
    auto ar_step = [&](const unsigned short* hb, unsigned short* hw, int st) {
        const float x0s = sm.x0T[st][n];
        f32x4 xi;
#pragma unroll
        for (int r = 0; r < 4; ++r) xi[r] = x0s * swx0v[r];

        f32x4 a1, a2, a3;
        f32x4 P = zero4;
#pragma unroll
        for (int c = 0; c < 4; ++c) {
            short8 bh = *(const short8*)(hb + c * 32 + 8 * q);
            short8 bl = *(const short8*)(hb + kHLO + c * 32 + 8 * q);
            if (c == 0) {
                a1 = __builtin_amdgcn_mfma_f32_16x16x32_bf16(fhh[0], bh, sbpv, 0, 0, 0);
                a2 = __builtin_amdgcn_mfma_f32_16x16x32_bf16(fhl[0], bh, zero4, 0, 0, 0);
                a3 = __builtin_amdgcn_mfma_f32_16x16x32_bf16(fhh[0], bl, xi,   0, 0, 0);
            } else {
                a1 = __builtin_amdgcn_mfma_f32_16x16x32_bf16(fhh[c], bh, a1, 0, 0, 0);
                a2 = __builtin_amdgcn_mfma_f32_16x16x32_bf16(fhl[c], bh, a2, 0, 0, 0);
                a3 = __builtin_amdgcn_mfma_f32_16x16x32_bf16(fhh[c], bl, a3, 0, 0, 0);
            }
            if (w == 0)   // output-pred partial: h_hi only (h_lo term ~3e-4, ES-smoothed)
                P = __builtin_amdgcn_mfma_f32_16x16x32_bf16(dh[c], bh, P, 0, 0, 0);
        }

        // ES stream -> LDS staging; wave 0, q==0 lanes own batch row n
        if (w == 0 && q == 0) {
            float pv = P[0] + bdv;
            es = (st == kLags) ? pv : fmaf(av, pv - es, es);
            sm.obuf[n][st - kLags] = es;
        }

        unsigned rb[4], db[4];
#pragma unroll
        for (int r = 0; r < 4; ++r) {
            float zs = (a1[r] + a2[r]) + a3[r];
            float hf = tanh_from_zs(zs);
            rb[r] = bf16_rne_hibits(hf);
            float d = hf - __builtin_bit_cast(float, rb[r]);
            db[r] = __builtin_bit_cast(unsigned, d);
        }
        uint2 uh, ul;
        uh.x = __builtin_amdgcn_perm(rb[1], rb[0], 0x07060302u);
        uh.y = __builtin_amdgcn_perm(rb[3], rb[2], 0x07060302u);
        ul.x = __builtin_amdgcn_perm(db[1], db[0], 0x07060302u);
        ul.y = __builtin_amdgcn_perm(db[3], db[2], 0x07060302u);
        const int wcol = w * 16 + q * 4;
        *(uint2*)(hw + wcol) = uh;
        *(uint2*)(hw + kHLO + wcol) = ul;
    };

    // ================= AR: st = 32..254, unrolled x2 (111 pairs + 1 tail) ==========
#pragma unroll 1
    for (int st = kLags; st < kSteps - 1; st += 2) {
        ar_step(h0, h1, st);       // even st: buf0 -> buf1
        __syncthreads();
        ar_step(h1, h0, st + 1);   // odd st:  buf1 -> buf0
        __syncthreads();
    }
    ar_step(h0, h1, kSteps - 1);   // st = 254 (even): buf0 -> buf1
    __syncthreads();

    // ================= tail: pred from h_255 (hi, in buf1) -> es -> col 223 ========
    if (w == 0) {
        f32x4 P = zero4;
#pragma unroll
        for (int c = 0; c < 4; ++c) {
            short8 bh = *(const short8*)(h1 + c * 32 + 8 * q);
            P = __builtin_amdgcn_mfma_f32_16x16x32_bf16(dh[c], bh, P, 0, 0, 0);
        }
        if (q == 0) {
            float pv = P[0] + bdv;
            es = fmaf(av, pv - es, es);
            sm.obuf[n][kOut - 1] = es;
        }
    }

    // ================= flush ES staging buffer to HBM (coalesced) =================
    __syncthreads();
    for (int idx = tid; idx < kMT * kOut; idx += kThreads) {
        const int mm = idx / kOut;
        const int t  = idx - mm * kOut;
        out[(size_t)(b0 + mm) * kOut + t] = sm.obuf[mm][t];
    }
}

}  // namespace

extern "C" void kernel_launch(void* const* d_in, const int* in_sizes, int n_in,
                              void* d_out, int out_size, void* d_ws, size_t ws_size,
                              hipStream_t stream) {
    const float* inputs = (const float*)d_in[0];
    const float* Wx     = (const float*)d_in[1];
    const float* Wh     = (const float*)d_in[2];
    const float* bias   = (const float*)d_in[3];
    const float* Wd     = (const float*)d_in[4];
    const float* bd     = (const float*)d_in[5];
    const float* alpha  = (const float*)d_in[6];
    // d_in[7] = lags (compile-time constant 32 here)

    arx_rnn_es_kernel<<<kB / kMT, kThreads, 0, stream>>>(
        inputs, Wx, Wh, bias, Wd, bd, alpha, (float*)d_out);
}